// Round 2
// 69.270 us; speedup vs baseline: 1.0004x; 1.0004x over previous
//
#include <hip/hip_runtime.h>
#include <math.h>

#define INV_SQRT2F 0.70710678118654752f

__device__ __forceinline__ float2 cmul(float2 a, float2 b) {
  return make_float2(a.x*b.x - a.y*b.y, a.x*b.y + a.y*b.x);
}
__device__ __forceinline__ float2 cmulc(float2 a, float2 b) { // a * conj(b)
  return make_float2(a.x*b.x + a.y*b.y, a.y*b.x - a.x*b.y);
}
__device__ __forceinline__ float2 cadd(float2 a, float2 b) {
  return make_float2(a.x + b.x, a.y + b.y);
}

// ---------------------------------------------------------------------------
// Fully fused kernel, one workgroup per batch row b.
// R7: fixes R6's LDS ordering hazard — gams[kidx] is now computed IN REGISTERS
// by the q==19 lanes inside phase 0 (|s0|^2,|s1|^2 are rotation-invariant, so
// the pre-fold register values give identical magnitudes; no LDS read against
// same-wave divergent writes). Everything else from R6 kept: 768 threads
// (12 waves), phase-2 blocks 1/3 on 2+2 waves, phase-4 fused (one barrier
// removed), phase-5 trig hoisted to phase 0 (reads only global l2 — safe).
// Blocks indexed kidx: 0->k0, 1->k1, 2->k3 (k=2 unused by reference).
// ---------------------------------------------------------------------------
__global__ __launch_bounds__(768) void iqp_fused_kernel(
    const float* __restrict__ x,    // (B,16,4,3)
    const float* __restrict__ pw,   // (16,2)
    const float* __restrict__ lw,   // (20,2): a1,b1
    const float* __restrict__ l2,   // (16,2): a2,b2
    const float* __restrict__ hw,   // (512,4)
    const float* __restrict__ hb,   // (512,)
    float* __restrict__ out)        // (B,512)
{
  const int b = blockIdx.x;
  const int t = threadIdx.x;
  const int lane = t & 63;
  const int wid = t >> 6;

  __shared__ float2 sqs[3][20][2];   // per-kidx single-qubit states (a1 folded)
  __shared__ float  b1s[20];
  __shared__ float2 gams[2];         // q19 gamma factor for kidx 0,1
  __shared__ float  trig[4][6];      // phase-5 per-k {ca,sa,cb1,sb1,cb2,sb2}
  __shared__ float2 W[3][4][8][33];  // [kidx][class][chunk x][u], padded pitch
  __shared__ float2 D0[8][64];       // block-0 chunk Grams [pair][x*8+y]
  __shared__ float2 ipv[6];          // block-1 ips: 00,11,22,33,01,23
  __shared__ float2 q3part[4][3];    // block-3 per-class partials: 00,01,11
  __shared__ float2 rho[256];        // rho4 block 0
  __shared__ float2 r012[64], r123[64], rk0[64], rk3[64];
  __shared__ float2 q0s[4], q3s[4];
  __shared__ float  e[4];
  __shared__ float  wsum[8];
  __shared__ float  nrm;

  // ---- phase 0: single-qubit states for blocks {0,1,3} -------------------
  if (t < 60) {
    const int kidx = t / 20, q = t % 20;
    const int k = (kidx == 2) ? 3 : kidx;
    const int pch = 4*k + q/5;
    const int j = q % 5;
    float2 s0, s1;
    if (j < 4) {
      const float* xp = x + ((size_t)((b*16 + pch)*4 + j))*3;
      float cx, sx, cy, sy, cz, sz;
      __sincosf(0.5f*xp[0], &sx, &cx);
      __sincosf(0.5f*xp[1], &sy, &cy);
      __sincosf(0.5f*xp[2], &sz, &cz);
      float2 w0 = make_float2(cy*cx,  sy*sx);
      float2 w1 = make_float2(sy*cx, -cy*sx);
      w0 = cmul(make_float2(cz, -sz), w0);
      w1 = cmul(make_float2(cz,  sz), w1);
      s0 = make_float2((w0.x + w1.x)*INV_SQRT2F, (w0.y + w1.y)*INV_SQRT2F);
      s1 = make_float2((w0.x - w1.x)*INV_SQRT2F, (w0.y - w1.y)*INV_SQRT2F);
    } else {
      float cx, sx, cy, sy;
      __sincosf(0.5f*pw[2*pch], &sx, &cx);
      __sincosf(0.5f*pw[2*pch + 1], &sy, &cy);
      const float2 w0 = make_float2(cy*cx,  sy*sx);
      const float2 w1 = make_float2(sy*cx, -cy*sx);
      s0 = make_float2((w0.x + w1.x)*INV_SQRT2F, (w0.y + w1.y)*INV_SQRT2F);
      s1 = make_float2((w0.x - w1.x)*INV_SQRT2F, (w0.y - w1.y)*INV_SQRT2F);
    }
    float ca, sa;
    __sincosf(0.5f*lw[2*q], &sa, &ca);
    sqs[kidx][q][0] = cmul(s0, make_float2(ca, -sa));
    sqs[kidx][q][1] = cmul(s1, make_float2(ca,  sa));
    if (kidx == 0) b1s[q] = lw[2*q + 1];
    // gam for kidx 0/1 from REGISTERS (no LDS read — R6's hazard removed).
    // |sqs[.][19][0]|^2 == |s0|^2 since the a1 fold is a pure phase.
    if (q == 19 && kidx < 2) {
      const float m0 = s0.x*s0.x + s0.y*s0.y;
      const float m1 = s1.x*s1.x + s1.y*s1.y;
      float sb, cb;
      __sincosf(lw[39], &sb, &cb);        // b1s[19] = lw[2*19+1]
      gams[kidx] = make_float2((m0 + m1)*cb, (m1 - m0)*sb);
    }
  } else if (t >= 64 && t < 68) {
    // independent of phase-0 LDS writes (reads only global l2)
    const int k = t - 64;
    const float alpha = l2[2*k];
    const float beta1 = l2[2*((k + 15) & 15) + 1];
    const float beta2 = l2[2*k + 1];
    float ca, sa, cb1, sb1, cb2, sb2;
    __sincosf(alpha, &sa, &ca);
    __sincosf(beta1, &sb1, &cb1);
    __sincosf(beta2, &sb2, &cb2);
    trig[k][0] = ca;  trig[k][1] = sa;
    trig[k][2] = cb1; trig[k][3] = sb1;
    trig[k][4] = cb2; trig[k][5] = sb2;
  }
  __syncthreads();

  // ---- phase 1: F per (kidx, class) wave; WHT except for kidx==1 ---------
  // r = (b0<<9)|(m<<1)|b9, m = j*64+lane. Qubit bits: q0=b0, q9=b9,
  // q1=j>>1, q2=j&1, q3..q8 = lane bits 5..0.
  {
    const int kk = wid >> 2;       // kidx (all 12 waves participate)
    const int cls = wid & 3;
    const int b0 = cls & 1, b9 = cls >> 1;

    int bq[10];                    // qubit bits (q3..q8 from lane)
    bq[0] = b0; bq[9] = b9;
    #pragma unroll
    for (int q = 3; q < 9; ++q) bq[q] = (lane >> (8 - q)) & 1;

    // base = sqs[0][b0] * prod(q=3..8) * sqs[9][b9], with phi_base folded
    float2 base = sqs[kk][0][b0];
    #pragma unroll
    for (int q = 3; q < 9; ++q) base = cmul(base, sqs[kk][q][bq[q]]);
    base = cmul(base, sqs[kk][9][b9]);
    {
      float phi = 0.f;
      #pragma unroll
      for (int q = 3; q < 9; ++q) {
        const float zq  = 1.f - 2.f*(float)bq[q];
        const float zq1 = 1.f - 2.f*(float)bq[q + 1];
        phi += b1s[q]*zq*zq1;
      }
      float sp, cp;
      __sincosf(0.5f*phi, &sp, &cp);
      base = cmul(base, make_float2(cp, -sp));
    }
    const float2 t0 = cmul(base, sqs[kk][1][0]);   // q1 bit = 0
    const float2 t1 = cmul(base, sqs[kk][1][1]);   // q1 bit = 1
    const float z0 = 1.f - 2.f*(float)b0;
    const float z3 = 1.f - 2.f*(float)bq[3];

    float2 v[4];
    #pragma unroll
    for (int j = 0; j < 4; ++j) {
      const int j1 = j >> 1, j0 = j & 1;
      const float z1 = 1.f - 2.f*(float)j1;
      const float z2 = 1.f - 2.f*(float)j0;
      const float phij = b1s[0]*z0*z1 + b1s[1]*z1*z2 + b1s[2]*z2*z3;
      float sp, cp;
      __sincosf(0.5f*phij, &sp, &cp);
      v[j] = cmul(cmul(j1 ? t1 : t0, sqs[kk][2][j0]), make_float2(cp, -sp));
    }

    if (kk != 1) {  // WHT (block 1 only needs Parseval-invariant ips)
      {
        float2 a0 = v[0], a2 = v[2];
        v[0] = cadd(a0, a2); v[2] = make_float2(a0.x - a2.x, a0.y - a2.y);
        float2 a1 = v[1], a3 = v[3];
        v[1] = cadd(a1, a3); v[3] = make_float2(a1.x - a3.x, a1.y - a3.y);
        a0 = v[0]; a1 = v[1];
        v[0] = cadd(a0, a1); v[1] = make_float2(a0.x - a1.x, a0.y - a1.y);
        a2 = v[2]; a3 = v[3];
        v[2] = cadd(a2, a3); v[3] = make_float2(a2.x - a3.x, a2.y - a3.y);
      }
      #pragma unroll
      for (int mask = 1; mask <= 32; mask <<= 1) {
        #pragma unroll
        for (int j = 0; j < 4; ++j) {
          const float px = __shfl_xor(v[j].x, mask);
          const float py = __shfl_xor(v[j].y, mask);
          if (lane & mask) v[j] = make_float2(px - v[j].x, py - v[j].y);
          else             v[j] = make_float2(v[j].x + px, v[j].y + py);
        }
      }
    }
    // normalized-WHT scale (8 stages -> 2^-4) ONLY where the WHT ran;
    // block 1 stores raw F so <F,F> comes out unscaled (Parseval).
    const float scl = (kk == 1) ? 1.0f : 0.0625f;
    #pragma unroll
    for (int j = 0; j < 4; ++j) {
      const int m = j*64 + lane;
      W[kk][cls][m >> 5][m & 31] =
          make_float2(v[j].x*scl, v[j].y*scl);
    }
  }
  __syncthreads();

  // ---- phase 2: contractions ---------------------------------------------
  if (wid < 8) {
    // block 0: full chunk-Gram, 512 outputs, 1 per thread
    const int pr = t >> 6, idx = t & 63, xx = idx >> 3, yy = idx & 7;
    const int pa = pr >> 1;
    const int pb = (pr & 1) + ((pr >> 2) << 1);
    float2 acc = make_float2(0.f, 0.f);
    #pragma unroll 8
    for (int u = 0; u < 32; ++u)
      acc = cadd(acc, cmulc(W[0][pa][xx][u], W[0][pb][yy][u]));
    D0[pr][xx*8 + yy] = acc;
  } else if (wid < 10) {
    // block 1: inner products <F_pa, F_pb>; 2 waves x 3 ips each
    const int u = wid - 8;
    const int prl[6][2] = {{0,0},{1,1},{2,2},{3,3},{0,1},{2,3}};
    #pragma unroll
    for (int rep = 0; rep < 3; ++rep) {
      const int which = u*3 + rep;
      const int pa = prl[which][0], pb = prl[which][1];
      float2 acc = make_float2(0.f, 0.f);
      #pragma unroll
      for (int jj = 0; jj < 4; ++jj) {
        const int m = jj*64 + lane;
        acc = cadd(acc, cmulc(W[1][pa][m >> 5][m & 31],
                              W[1][pb][m >> 5][m & 31]));
      }
      for (int off = 32; off > 0; off >>= 1) {
        acc.x += __shfl_down(acc.x, off);
        acc.y += __shfl_down(acc.y, off);
      }
      if (lane == 0) ipv[which] = acc;
    }
  } else {
    // block 3 (kidx 2): partial diagonal strips; 2 waves x 2 classes each
    const int u = wid - 10;
    const int lo = lane >> 4;
    const int u0 = (lane & 15)*2;
    #pragma unroll
    for (int cc = 0; cc < 2; ++cc) {
      const int c = u*2 + cc;
      float2 a00 = make_float2(0.f, 0.f), a01 = a00, a11 = a00;
      #pragma unroll
      for (int du = 0; du < 2; ++du) {
        const float2 p0 = W[2][c][(lo << 1)    ][u0 + du];
        const float2 p1 = W[2][c][(lo << 1) | 1][u0 + du];
        a00 = cadd(a00, cmulc(p0, p0));
        a01 = cadd(a01, cmulc(p0, p1));
        a11 = cadd(a11, cmulc(p1, p1));
      }
      for (int off = 32; off > 0; off >>= 1) {
        a00.x += __shfl_down(a00.x, off); a00.y += __shfl_down(a00.y, off);
        a01.x += __shfl_down(a01.x, off); a01.y += __shfl_down(a01.y, off);
        a11.x += __shfl_down(a11.x, off); a11.y += __shfl_down(a11.y, off);
      }
      if (lane == 0) {
        q3part[c][0] = a00; q3part[c][1] = a01; q3part[c][2] = a11;
      }
    }
  }
  __syncthreads();

  // ---- phase 3: assemble rho (block 0), q0 (block 1), q3 (block 3) -------
  if (t < 256) {
    const int i = t >> 4, j = t & 15;
    const int xy = (i & 7)*8 + (j & 7);
    const int si = i >> 3, sj = j >> 3;
    const float2 gam = gams[0];
    float2 acc = cadd(D0[0][xy], D0[4][xy]);                 // (0,0)+(2,2)
    {
      const float2 t2 = cadd(D0[3][xy], D0[7][xy]);          // (1,1)+(3,3)
      const float sg = ((si ^ sj) & 1) ? -1.f : 1.f;
      acc.x += sg*t2.x; acc.y += sg*t2.y;
    }
    {
      float2 t3 = cadd(D0[1][xy], D0[5][xy]);                // (0,1)+(2,3)
      t3 = cmul(gam, t3);
      const float sg = (sj & 1) ? -1.f : 1.f;
      acc.x += sg*t3.x; acc.y += sg*t3.y;
    }
    {
      float2 t4 = cadd(D0[2][xy], D0[6][xy]);                // (1,0)+(3,2)
      t4 = cmulc(t4, gam);
      const float sg = (si & 1) ? -1.f : 1.f;
      acc.x += sg*t4.x; acc.y += sg*t4.y;
    }
    rho[t] = make_float2(0.5f*acc.x, 0.5f*acc.y);
  } else if (t < 260) {
    // q0[p][q] = 0.5( T04 + (-1)^{p^q} T37 + (-1)^q gam1 T15
    //                 + (-1)^p conj(gam1 T15) )
    const int pp = (t - 256) >> 1, qq = (t - 256) & 1;
    const float2 gam1 = gams[1];
    const float2 T04 = cadd(ipv[0], ipv[2]);
    const float2 T37 = cadd(ipv[1], ipv[3]);
    const float2 T15 = cadd(ipv[4], ipv[5]);
    const float2 h = cmul(gam1, T15);
    float2 acc = T04;
    const float sg1 = ((pp ^ qq) & 1) ? -1.f : 1.f;
    acc.x += sg1*T37.x; acc.y += sg1*T37.y;
    const float sgq = (qq & 1) ? -1.f : 1.f;
    acc.x += sgq*h.x; acc.y += sgq*h.y;
    const float sgp = (pp & 1) ? -1.f : 1.f;
    acc.x += sgp*h.x; acc.y -= sgp*h.y;   // + sgp * conj(h)
    q0s[pp*2 + qq] = make_float2(0.5f*acc.x, 0.5f*acc.y);
  } else if (t < 264) {
    const int ei = t - 260;               // (p,q) = (ei>>1, ei&1)
    const int pp = ei >> 1, qq = ei & 1;
    const int src = (pp == 0 && qq == 0) ? 0 : (pp == 1 && qq == 1) ? 2 : 1;
    float2 s = make_float2(0.f, 0.f);
    #pragma unroll
    for (int c = 0; c < 4; ++c) s = cadd(s, q3part[c][src]);
    if (pp == 1 && qq == 0) s.y = -s.y;   // conj for (1,0)
    q3s[pp*2 + qq] = s;
  }
  __syncthreads();

  // ---- phase 4 (fused): partial traces + rk0/rk3 directly from rho -------
  if (t < 64) {
    const int i = t >> 3, j = t & 7;
    r012[t] = cadd(rho[(2*i)*16 + 2*j], rho[(2*i + 1)*16 + 2*j + 1]);
    r123[t] = cadd(rho[i*16 + j], rho[(i + 8)*16 + (j + 8)]);
    // rk0 = q3s[si,sj] * r01[i&3, j&3];  r01[p,q] = sum_w rho[4p+w, 4q+w]
    {
      const int ip = i & 3, jp = j & 3;
      float2 s1 = make_float2(0.f, 0.f);
      #pragma unroll
      for (int w = 0; w < 4; ++w)
        s1 = cadd(s1, rho[(4*ip + w)*16 + 4*jp + w]);
      rk0[t] = cmul(q3s[(i >> 2)*2 + (j >> 2)], s1);
    }
    // rk3 = r23[i>>1, j>>1] * q0s[i&1, j&1]; r23[p,q] = sum_w rho[4w+p, 4w+q]
    {
      const int ip = i >> 1, jp = j >> 1;
      float2 s2 = make_float2(0.f, 0.f);
      #pragma unroll
      for (int w = 0; w < 4; ++w)
        s2 = cadd(s2, rho[(4*w + ip)*16 + 4*w + jp]);
      rk3[t] = cmul(s2, q0s[(i & 1)*2 + (j & 1)]);
    }
  }
  __syncthreads();

  // ---- phase 5: Heisenberg expectations ----------------------------------
  if (t < 256) {
    const int k = t >> 6;
    const int idx = t & 63;
    const int i = idx >> 3, j = idx & 7;
    const float ca  = trig[k][0], sa  = trig[k][1];
    const float cb1 = trig[k][2], sb1 = trig[k][3];
    const float cb2 = trig[k][4], sb2 = trig[k][5];
    float2 m1, m2;
    {
      const int xr = i ^ j;
      m1 = (xr == 0) ? make_float2( cb1*cb2, 0.f)
         : (xr == 3) ? make_float2( 0.f,    -cb1*sb2)
         : (xr == 6) ? make_float2( 0.f,    -sb1*cb2)
         : (xr == 5) ? make_float2(-sb1*sb2, 0.f)
         : make_float2(0.f, 0.f);
      const int xr2 = xr ^ 2;
      m2 = (xr2 == 0) ? make_float2( cb1*cb2, 0.f)
         : (xr2 == 3) ? make_float2( 0.f,    -cb1*sb2)
         : (xr2 == 6) ? make_float2( 0.f,    -sb1*cb2)
         : (xr2 == 5) ? make_float2(-sb1*sb2, 0.f)
         : make_float2(0.f, 0.f);
    }
    float2 O = make_float2(ca*m1.x + sa*m2.y, ca*m1.y - sa*m2.x);
    if ((i >> 1) & 1) { O.x = -O.x; O.y = -O.y; }
    const float2* rp = (k == 0) ? rk0 : (k == 1) ? r012 : (k == 2) ? r123 : rk3;
    const float2 rv = rp[j*8 + i];
    float contrib = O.x*rv.x - O.y*rv.y;
    for (int off = 32; off > 0; off >>= 1) contrib += __shfl_down(contrib, off);
    if (idx == 0) e[k] = contrib;
  }
  __syncthreads();

  // ---- phase 6: head + L2 normalize --------------------------------------
  float val = 0.f;
  if (t < 512) {
    val = hb[t] + e[0]*hw[4*t] + e[1]*hw[4*t + 1]
        + e[2]*hw[4*t + 2] + e[3]*hw[4*t + 3];
    float ss = val*val;
    for (int off = 32; off > 0; off >>= 1) ss += __shfl_down(ss, off);
    if ((t & 63) == 0) wsum[t >> 6] = ss;
  }
  __syncthreads();
  if (t == 0) {
    float s = 0.f;
    for (int w = 0; w < 8; ++w) s += wsum[w];
    nrm = fmaxf(sqrtf(s), 1e-12f);
  }
  __syncthreads();
  if (t < 512) out[(size_t)b*512 + t] = val / nrm;
}

extern "C" void kernel_launch(void* const* d_in, const int* in_sizes, int n_in,
                              void* d_out, int out_size, void* d_ws, size_t ws_size,
                              hipStream_t stream) {
  const float* x  = (const float*)d_in[0];  // (B,16,4,3)
  const float* pw = (const float*)d_in[1];  // (16,2)
  const float* lw = (const float*)d_in[2];  // (20,2)
  const float* l2 = (const float*)d_in[3];  // (16,2)
  const float* hw = (const float*)d_in[4];  // (512,4)
  const float* hb = (const float*)d_in[5];  // (512,)
  const int B = in_sizes[0] / (16*4*3);

  iqp_fused_kernel<<<B, 768, 0, stream>>>(x, pw, lw, l2, hw, hb, (float*)d_out);
}